// Round 7
// baseline (152.114 us; speedup 1.0000x reference)
//
#include <hip/hip_runtime.h>
#include <hip/hip_bf16.h>
#include <math.h>

#define B_   64
#define N_   8192
#define D_   256
#define K_   16
#define EPS_ 1e-8f
#define NEG_ -3.4e38f

// ws layout (float units)
static const size_t SIM_OFF   = 0;              // B_*N_ = 524288
static const size_t CANDV_OFF = 524288;         // 8192 segs * 16 = 131072
static const size_t CANDI_OFF = 655360;         // 131072 ints
static const size_t XBUF_OFF  = 786432;         // B_*D_*K_ = 262144
static const size_t QKV_OFF   = 1048576;        // B_*3*K_*D_ = 786432

// ---------------------------------------------------------------------------
// A: sim stream, deep pipeline. 2048 blocks x 256; wave = 64-row segment.
// Per iter t (8 iters): 16-lane group g computes rows n0+8t+2g, +1 (2 rows),
// while the NEXT iter's 2 rows are already in flight -> 8 KB outstanding
// per wave. __launch_bounds__(256,4) guarantees >=4 waves/SIMD so the SIMD
// round-robin covers HBM latency (5 waves x ~340cy compute > 900cy).
// ---------------------------------------------------------------------------
__global__ void __launch_bounds__(256, 4)
sim_kernel(const float* __restrict__ q, const float* __restrict__ km,
           const int* __restrict__ iter, float* __restrict__ sim) {
    int tid = threadIdx.x;
    int w = tid >> 6, lane = tid & 63;
    int g = lane >> 4, p = lane & 15;
    int seg = (blockIdx.x << 2) + w;            // [0, 8192)
    int b   = seg >> 7;
    int n0  = (seg & 127) << 6;
    int it  = iter[b];
    float* simb = sim + (size_t)b * N_;

    if (n0 > it) { simb[n0 + lane] = 0.f; return; }

    float4 q4[4];
    #pragma unroll
    for (int kk = 0; kk < 4; kk++)
        q4[kk] = *(const float4*)(q + (size_t)b * D_ + kk * 64 + p * 4);
    float qq = q4[0].x*q4[0].x + q4[0].y*q4[0].y + q4[0].z*q4[0].z + q4[0].w*q4[0].w
             + q4[1].x*q4[1].x + q4[1].y*q4[1].y + q4[1].z*q4[1].z + q4[1].w*q4[1].w
             + q4[2].x*q4[2].x + q4[2].y*q4[2].y + q4[2].z*q4[2].z + q4[2].w*q4[2].w
             + q4[3].x*q4[3].x + q4[3].y*q4[3].y + q4[3].z*q4[3].z + q4[3].w*q4[3].w;
    #pragma unroll
    for (int off = 8; off; off >>= 1) qq += __shfl_xor(qq, off);
    float qn = sqrtf(qq);

    const float* kmb = km + (size_t)b * N_ * D_;
    int p4 = p * 4;

    // prologue: pair for t=0
    float4 a0, a1, a2, a3, b0, b1, b2, b3;
    {
        int ra = n0 + (g << 1);
        const float* pa = kmb + (size_t)min(ra,     it) * D_ + p4;
        const float* pb = kmb + (size_t)min(ra + 1, it) * D_ + p4;
        a0 = *(const float4*)(pa);       a1 = *(const float4*)(pa +  64);
        a2 = *(const float4*)(pa + 128); a3 = *(const float4*)(pa + 192);
        b0 = *(const float4*)(pb);       b1 = *(const float4*)(pb +  64);
        b2 = *(const float4*)(pb + 128); b3 = *(const float4*)(pb + 192);
    }

    for (int t = 0; t < 8; t++) {
        int ra = n0 + (t << 3) + (g << 1);
        int nx = (t < 7) ? (ra + 8) : it;       // next pair (dummy hot on last)
        const float* pa = kmb + (size_t)min(nx,     it) * D_ + p4;
        const float* pb = kmb + (size_t)min(nx + 1, it) * D_ + p4;
        float4 xa0 = *(const float4*)(pa);       float4 xa1 = *(const float4*)(pa +  64);
        float4 xa2 = *(const float4*)(pa + 128); float4 xa3 = *(const float4*)(pa + 192);
        float4 xb0 = *(const float4*)(pb);       float4 xb1 = *(const float4*)(pb +  64);
        float4 xb2 = *(const float4*)(pb + 128); float4 xb3 = *(const float4*)(pb + 192);

        float dota = a0.x*q4[0].x + a0.y*q4[0].y + a0.z*q4[0].z + a0.w*q4[0].w
                   + a1.x*q4[1].x + a1.y*q4[1].y + a1.z*q4[1].z + a1.w*q4[1].w
                   + a2.x*q4[2].x + a2.y*q4[2].y + a2.z*q4[2].z + a2.w*q4[2].w
                   + a3.x*q4[3].x + a3.y*q4[3].y + a3.z*q4[3].z + a3.w*q4[3].w;
        float sqa  = a0.x*a0.x + a0.y*a0.y + a0.z*a0.z + a0.w*a0.w
                   + a1.x*a1.x + a1.y*a1.y + a1.z*a1.z + a1.w*a1.w
                   + a2.x*a2.x + a2.y*a2.y + a2.z*a2.z + a2.w*a2.w
                   + a3.x*a3.x + a3.y*a3.y + a3.z*a3.z + a3.w*a3.w;
        float dotb = b0.x*q4[0].x + b0.y*q4[0].y + b0.z*q4[0].z + b0.w*q4[0].w
                   + b1.x*q4[1].x + b1.y*q4[1].y + b1.z*q4[1].z + b1.w*q4[1].w
                   + b2.x*q4[2].x + b2.y*q4[2].y + b2.z*q4[2].z + b2.w*q4[2].w
                   + b3.x*q4[3].x + b3.y*q4[3].y + b3.z*q4[3].z + b3.w*q4[3].w;
        float sqb  = b0.x*b0.x + b0.y*b0.y + b0.z*b0.z + b0.w*b0.w
                   + b1.x*b1.x + b1.y*b1.y + b1.z*b1.z + b1.w*b1.w
                   + b2.x*b2.x + b2.y*b2.y + b2.z*b2.z + b2.w*b2.w
                   + b3.x*b3.x + b3.y*b3.y + b3.z*b3.z + b3.w*b3.w;
        #pragma unroll
        for (int off = 8; off; off >>= 1) {     // 4 independent chains
            dota += __shfl_xor(dota, off);
            sqa  += __shfl_xor(sqa,  off);
            dotb += __shfl_xor(dotb, off);
            sqb  += __shfl_xor(sqb,  off);
        }
        float sa = (ra     <= it) ? dota / fmaxf(sqrtf(sqa) * qn, EPS_) : 0.f;
        float sb = (ra + 1 <= it) ? dotb / fmaxf(sqrtf(sqb) * qn, EPS_) : 0.f;
        if (p == 0) { simb[ra] = sa; simb[ra + 1] = sb; }
        a0 = xa0; a1 = xa1; a2 = xa2; a3 = xa3;
        b0 = xb0; b1 = xb1; b2 = xb2; b3 = xb3;
    }
}

// ---------------------------------------------------------------------------
// B: per-64-row-segment top-16 candidates via wave64 bitonic sort.
// ---------------------------------------------------------------------------
__global__ void __launch_bounds__(256)
cand_kernel(const float* __restrict__ sim,
            float* __restrict__ cand_v, int* __restrict__ cand_i) {
    int tid = threadIdx.x;
    int w = tid >> 6, lane = tid & 63;
    int seg = (blockIdx.x << 2) + w;
    int b   = seg >> 7;
    int n0  = (seg & 127) << 6;
    float v  = sim[(size_t)b * N_ + n0 + lane];
    int  idx = n0 + lane;
    #pragma unroll
    for (int k = 2; k <= 64; k <<= 1) {
        #pragma unroll
        for (int j = k >> 1; j > 0; j >>= 1) {
            float pv = __shfl_xor(v, j);
            int   pi = __shfl_xor(idx, j);
            bool up         = ((lane & k) == 0);
            bool is_lower   = ((lane & j) == 0);
            bool mine_first = (v > pv) || (v == pv && idx < pi);
            bool take_mine  = ((is_lower == up) == mine_first);
            if (!take_mine) { v = pv; idx = pi; }
        }
    }
    if (lane < K_) {
        cand_v[(size_t)seg * K_ + lane] = v;
        cand_i[(size_t)seg * K_ + lane] = idx;
    }
}

// ---------------------------------------------------------------------------
// C: merge 2048 cands (single wave) + softmax + gather scaled x to GLOBAL
// xbuf[b][d][k] (so the qkv kernel can read it via uniform/scalar loads).
// 64 blocks x 256.
// ---------------------------------------------------------------------------
__global__ void __launch_bounds__(256)
merge_gather_kernel(const float* __restrict__ cand_v, const int* __restrict__ cand_i,
                    const float* __restrict__ vm, const int* __restrict__ iter,
                    float* __restrict__ xbuf) {
    int b = blockIdx.x;
    int tid = threadIdx.x, lane = tid & 63;
    int it = iter[b];
    if (it == 0) return;                        // attn_out emits zeros

    __shared__ int   seli[K_];
    __shared__ float scl[K_];

    if (tid < 64) {
        float cv[32]; int ci[32];
        #pragma unroll
        for (int j = 0; j < 32; j++) {
            cv[j] = cand_v[(size_t)b * 2048 + (j << 6) + lane];
            ci[j] = cand_i[(size_t)b * 2048 + (j << 6) + lane];
        }
        float selv[K_]; int selidx[K_];
        for (int sel = 0; sel < K_; sel++) {
            float bv = cv[0]; int bi = ci[0];
            #pragma unroll
            for (int j = 1; j < 32; j++)
                if (cv[j] > bv || (cv[j] == bv && ci[j] < bi)) { bv = cv[j]; bi = ci[j]; }
            #pragma unroll
            for (int off = 32; off; off >>= 1) {
                float ov = __shfl_xor(bv, off);
                int   oi = __shfl_xor(bi, off);
                if (ov > bv || (ov == bv && oi < bi)) { bv = ov; bi = oi; }
            }
            #pragma unroll
            for (int j = 0; j < 32; j++)
                if (ci[j] == bi) cv[j] = NEG_;
            selv[sel] = bv; selidx[sel] = bi;
            if (lane == 0) seli[sel] = bi;
        }
        float m = NEG_;
        #pragma unroll
        for (int jj = 0; jj < K_; jj++) m = fmaxf(m, selv[jj]);
        float ssum = 0.f;
        #pragma unroll
        for (int jj = 0; jj < K_; jj++) ssum += expf(selv[jj] - m);
        if (lane < K_) {
            float wgt = expf(selv[lane] - m) / ssum;
            scl[lane] = (selidx[lane] <= it) ? wgt : 0.f;   // masked pick -> 0
        }
    }
    __syncthreads();

    float* xb = xbuf + (size_t)b * (D_ * K_);   // [d][k], thread = d
    #pragma unroll
    for (int kk = 0; kk < K_; kk += 4) {
        float4 px;
        px.x = scl[kk+0] * vm[((size_t)b * N_ + seli[kk+0]) * D_ + tid];
        px.y = scl[kk+1] * vm[((size_t)b * N_ + seli[kk+1]) * D_ + tid];
        px.z = scl[kk+2] * vm[((size_t)b * N_ + seli[kk+2]) * D_ + tid];
        px.w = scl[kk+3] * vm[((size_t)b * N_ + seli[kk+3]) * D_ + tid];
        *(float4*)(xb + tid * K_ + kk) = px;    // 64B/thread, coalesced
    }
}

// ---------------------------------------------------------------------------
// D: qkv projection. 192 blocks (b,which) x 256, thread = e.
// x read from global via wave-uniform addresses (scalar-load/L1-broadcast
// path, no LDS pipe). W row per thread, contiguous float4.
// ---------------------------------------------------------------------------
__global__ void __launch_bounds__(256)
qkv_kernel(const float* __restrict__ xbuf, const int* __restrict__ iter,
           const float* __restrict__ inw, const float* __restrict__ inb,
           float* __restrict__ qkv) {
    int bwh = blockIdx.x;
    int b = bwh / 3, which = bwh - b * 3;
    if (iter[b] == 0) return;                   // attn_out emits zeros
    int tid = threadIdx.x;

    float acc[K_];
    #pragma unroll
    for (int k = 0; k < K_; k++) acc[k] = 0.f;
    const float* wrow = inw + (size_t)(which * D_ + tid) * D_;
    const float* xb   = xbuf + (size_t)b * (D_ * K_);
    for (int d = 0; d < D_; d += 4) {
        float4 wv4 = *(const float4*)(wrow + d);
        float wk[4] = {wv4.x, wv4.y, wv4.z, wv4.w};
        #pragma unroll
        for (int dd = 0; dd < 4; dd++) {
            float wgt = wk[dd];
            const float* xr = xb + (d + dd) * K_;            // wave-uniform
            float4 x0 = *(const float4*)(xr);
            float4 x1 = *(const float4*)(xr + 4);
            float4 x2 = *(const float4*)(xr + 8);
            float4 x3 = *(const float4*)(xr + 12);
            acc[0]  += x0.x * wgt; acc[1]  += x0.y * wgt; acc[2]  += x0.z * wgt; acc[3]  += x0.w * wgt;
            acc[4]  += x1.x * wgt; acc[5]  += x1.y * wgt; acc[6]  += x1.z * wgt; acc[7]  += x1.w * wgt;
            acc[8]  += x2.x * wgt; acc[9]  += x2.y * wgt; acc[10] += x2.z * wgt; acc[11] += x2.w * wgt;
            acc[12] += x3.x * wgt; acc[13] += x3.y * wgt; acc[14] += x3.z * wgt; acc[15] += x3.w * wgt;
        }
    }
    float bias = inb[which * D_ + tid];
    #pragma unroll
    for (int k = 0; k < K_; k++)
        qkv[(((size_t)b * 3 + which) * K_ + k) * D_ + tid] = acc[k] + bias;
}

// ---------------------------------------------------------------------------
// E: attention (token-sum commutes -> colsum) + output projection. 64 blocks.
// ---------------------------------------------------------------------------
__global__ void __launch_bounds__(256)
attn_out_kernel(const float* __restrict__ qkv, const int* __restrict__ iter,
                const float* __restrict__ ow, const float* __restrict__ ob,
                float* __restrict__ out) {
    int b = blockIdx.x, tid = threadIdx.x;
    int it = iter[b];
    if (it == 0) { out[(size_t)b * D_ + tid] = 0.f; return; }
    __shared__ float qs[K_][260];
    __shared__ float ks[K_][260];
    __shared__ float vs[K_][260];
    __shared__ float attn[K_][K_];
    __shared__ float colsum[K_];
    __shared__ float so[D_];
    const float* base = qkv + (size_t)b * 3 * K_ * D_;
    #pragma unroll
    for (int k = 0; k < K_; k++) {
        qs[k][tid] = base[(0 * K_ + k) * D_ + tid];
        ks[k][tid] = base[(1 * K_ + k) * D_ + tid];
        vs[k][tid] = base[(2 * K_ + k) * D_ + tid];
    }
    __syncthreads();
    int i = tid >> 4, j = tid & 15;
    float s = 0.f;
    for (int d4 = 0; d4 < 64; d4++) {
        float4 qv = *(const float4*)(&qs[i][d4 * 4]);
        float4 kv = *(const float4*)(&ks[j][d4 * 4]);
        s += qv.x*kv.x + qv.y*kv.y + qv.z*kv.z + qv.w*kv.w;
    }
    attn[i][j] = s * 0.0625f;                   // 1/sqrt(256)
    __syncthreads();
    if (tid < K_) {
        float m = NEG_;
        for (int jj = 0; jj < K_; jj++) m = fmaxf(m, attn[tid][jj]);
        float ssum = 0.f;
        for (int jj = 0; jj < K_; jj++) ssum += expf(attn[tid][jj] - m);
        float inv = 1.f / ssum;
        for (int jj = 0; jj < K_; jj++) attn[tid][jj] = expf(attn[tid][jj] - m) * inv;
    }
    __syncthreads();
    if (tid < K_) {
        float c = 0.f;
        for (int ii = 0; ii < K_; ii++) c += attn[ii][tid];
        colsum[tid] = c;
    }
    __syncthreads();
    float acc = 0.f;
    #pragma unroll
    for (int jj = 0; jj < K_; jj++) acc += colsum[jj] * vs[jj][tid];
    so[tid] = acc;
    __syncthreads();
    float o = 0.f;
    const float* orow = ow + (size_t)tid * D_;
    for (int e = 0; e < D_; e += 4) {
        float4 wv = *(const float4*)(orow + e);
        float4 sv = *(const float4*)(&so[e]);
        o += sv.x*wv.x + sv.y*wv.y + sv.z*wv.z + sv.w*wv.w;
    }
    out[(size_t)b * D_ + tid] = o + 16.f * ob[tid];
}

extern "C" void kernel_launch(void* const* d_in, const int* in_sizes, int n_in,
                              void* d_out, int out_size, void* d_ws, size_t ws_size,
                              hipStream_t stream) {
    const float* q   = (const float*)d_in[0];
    const float* km  = (const float*)d_in[1];
    const float* vm  = (const float*)d_in[2];
    const int*   it  = (const int*)  d_in[3];
    const float* inw = (const float*)d_in[4];
    const float* inb = (const float*)d_in[5];
    const float* ow  = (const float*)d_in[6];
    const float* ob  = (const float*)d_in[7];
    float* out = (float*)d_out;

    float* ws     = (float*)d_ws;
    float* sim    = ws + SIM_OFF;
    float* cand_v = ws + CANDV_OFF;
    int*   cand_i = (int*)(ws + CANDI_OFF);
    float* xbuf   = ws + XBUF_OFF;
    float* qkv    = ws + QKV_OFF;

    sim_kernel<<<dim3(2048), dim3(256), 0, stream>>>(q, km, it, sim);
    cand_kernel<<<dim3(2048), dim3(256), 0, stream>>>(sim, cand_v, cand_i);
    merge_gather_kernel<<<dim3(B_), dim3(256), 0, stream>>>(cand_v, cand_i, vm, it, xbuf);
    qkv_kernel<<<dim3(B_ * 3), dim3(256), 0, stream>>>(xbuf, it, inw, inb, qkv);
    attn_out_kernel<<<dim3(B_), dim3(256), 0, stream>>>(qkv, it, ow, ob, out);
}